// Round 6
// baseline (233.247 us; speedup 1.0000x reference)
//
#include <hip/hip_runtime.h>
#include <hip/hip_fp16.h>
#include <stdint.h>

typedef _Float16 f16;
typedef f16   f16x8 __attribute__((ext_vector_type(8)));
typedef float f32x4 __attribute__((ext_vector_type(4)));

#define NTOK 262144
#define DDIM 256
#define KCB  1024
#define GG   4
#define CC   64
#define FR   4                          // 16-row fragments per wave (64 rows/wave)
#define ROWS_PER_BLK (FR * 16 * 4)      // 256
#define NBLKX (NTOK / ROWS_PER_BLK)     // 1024
#define NPART (NBLKX * GG)              // 4096 per-block loss partials
#define TILE_K 64                       // codes per staged LDS tile
#define NTILE  (KCB / TILE_K)           // 16
#define TILE_B (TILE_K * CC * 2)        // 8192 bytes of fp16 codes per tile

static __device__ __forceinline__ uint32_t umin32(uint32_t a, uint32_t b) { return a < b ? a : b; }

typedef __attribute__((address_space(1))) const void gv_t;
typedef __attribute__((address_space(3))) void lv_t;
static __device__ __forceinline__ void gl_lds16(const void* g, void* l) {
    __builtin_amdgcn_global_load_lds((gv_t*)g, (lv_t*)l, 16, 0, 0);
}
static __device__ __forceinline__ void gl_lds4(const void* g, void* l) {
    __builtin_amdgcn_global_load_lds((gv_t*)g, (lv_t*)l, 4, 0, 0);
}

// ---------------- prep: fp32 codebook -> fp16 copy + (0.5 + ||e||^2) table
__global__ __launch_bounds__(64) void vq_prep(const float* __restrict__ cb,
                                              f16* __restrict__ cb16,
                                              float* __restrict__ esq05) {
    int gk = blockIdx.x;          // 0 .. G*K-1
    int c  = threadIdx.x;         // 0 .. 63
    float v = cb[(size_t)gk * CC + c];
    cb16[(size_t)gk * CC + c] = (f16)v;
    float s = v * v;
    #pragma unroll
    for (int off = 32; off; off >>= 1) s += __shfl_down(s, off, 64);
    if (c == 0) esq05[gk] = 0.5f + s;
}

// ---------------- kernel 1: LDS-staged codebook + MFMA + packed-key argmin -> u16 idx + loss partial
__global__ __launch_bounds__(256, 4) void vq_argmin(const float* __restrict__ z,
                                                    const f16* __restrict__ cb16,
                                                    const float* __restrict__ esq05,
                                                    unsigned short* __restrict__ idx,
                                                    float* __restrict__ part) {
    const int lane = threadIdx.x & 63;
    const int w    = threadIdx.x >> 6;                 // wave id (0..3)
    const int g    = blockIdx.y;                       // group
    const int r0   = blockIdx.x * ROWS_PER_BLK + w * (FR * 16);  // wave's base row
    const int q    = lane >> 4;                        // quarter (k-chunk selector)
    const int t    = lane & 15;                        // within-16 id

    // double-buffered codebook tile (swizzled image) + e tile
    __shared__ __align__(16) char sb[2][TILE_B + 256];
    __shared__ float ls[4];

    const f16*   cbg = cb16  + (size_t)g * KCB * CC;
    const float* eg  = esq05 + (size_t)g * KCB;

    // stage tile: pre-swizzled per-lane SOURCE, linear global_load_lds dest (G21),
    // swizzled ds_read below. LDS[code*128 + b'] = logical(code, b' ^ ((code&7)<<4)).
    #define STAGE(tile, bufsel)                                                      \
        do {                                                                         \
            const char* gtile = (const char*)cbg + (size_t)(tile) * TILE_B;          \
            _Pragma("unroll")                                                        \
            for (int c2 = 0; c2 < 2; ++c2) {                                         \
                uint32_t x  = (uint32_t)(w * 2048 + c2 * 1024 + lane * 16);          \
                uint32_t gx = x ^ (((x >> 7) & 7u) << 4);                            \
                gl_lds16(gtile + gx, &sb[bufsel][w * 2048 + c2 * 1024]);             \
            }                                                                        \
            if (w == 0) gl_lds4(eg + (tile) * TILE_K + lane, &sb[bufsel][TILE_B]);   \
        } while (0)

    // ---- issue stage of tile 0 first so it overlaps the z prologue
    STAGE(0, 0);

    // ---- load A fragments (FR x 16 rows, K=64 in two 32-halves), fp32 -> fp16, scaled by -2
    // A layout for mfma_f32_16x16x32_f16: lane holds row (lane&15), k = (lane>>4)*8 + j
    f16x8 a[FR][2];
    float zsq[FR];
    #pragma unroll
    for (int f = 0; f < FR; ++f) {
        int row = r0 + f * 16 + t;
        const float* zp = z + (size_t)row * DDIM + g * CC + q * 8;
        float4 v0 = *(const float4*)(zp);
        float4 v1 = *(const float4*)(zp + 4);
        float4 v2 = *(const float4*)(zp + 32);
        float4 v3 = *(const float4*)(zp + 36);
        f16x8 a0 = { (f16)(-2.f*v0.x),(f16)(-2.f*v0.y),(f16)(-2.f*v0.z),(f16)(-2.f*v0.w),
                     (f16)(-2.f*v1.x),(f16)(-2.f*v1.y),(f16)(-2.f*v1.z),(f16)(-2.f*v1.w) };
        f16x8 a1 = { (f16)(-2.f*v2.x),(f16)(-2.f*v2.y),(f16)(-2.f*v2.z),(f16)(-2.f*v2.w),
                     (f16)(-2.f*v3.x),(f16)(-2.f*v3.y),(f16)(-2.f*v3.z),(f16)(-2.f*v3.w) };
        a[f][0] = a0; a[f][1] = a1;
        float s = v0.x*v0.x + v0.y*v0.y + v0.z*v0.z + v0.w*v0.w
                + v1.x*v1.x + v1.y*v1.y + v1.z*v1.z + v1.w*v1.w
                + v2.x*v2.x + v2.y*v2.y + v2.z*v2.z + v2.w*v2.w
                + v3.x*v3.x + v3.y*v3.y + v3.z*v3.z + v3.w*v3.w;
        s += __shfl_xor(s, 16, 64);
        s += __shfl_xor(s, 32, 64);
        zsq[f] = s;   // lane l holds full ||z_g||^2 for row (l&15)
    }

    uint32_t run[FR][4];
    #pragma unroll
    for (int f = 0; f < FR; ++f)
        #pragma unroll
        for (int i = 0; i < 4; ++i) run[f][i] = 0xFFFFFFFFu;

    // per-lane constant part of the swizzled ds_read address (b0); b1 = ^64
    const uint32_t binner = (uint32_t)t * 128 + (((uint32_t)(q * 16)) ^ (((uint32_t)(t & 7)) << 4));

    // ---- tile loop: one barrier per tile; stage(t+1) in flight across compute(t)
    for (int tt = 0; tt < NTILE; ++tt) {
        __syncthreads();                               // stage(tt) landed; all waves done with other buf
        if (tt + 1 < NTILE) STAGE(tt + 1, (tt + 1) & 1);
        const char*  bb = sb[tt & 1];
        const float* eb = (const float*)(sb[tt & 1] + TILE_B);
        #pragma unroll
        for (int sub = 0; sub < 4; ++sub) {
            f16x8 b0 = *(const f16x8*)(bb + sub * 2048 + binner);
            f16x8 b1 = *(const f16x8*)(bb + sub * 2048 + (binner ^ 64));
            float e  = eb[sub * 16 + t];
            f32x4 ce = { e, e, e, e };                 // d = (0.5+esq) + (-2z)·e
            uint32_t code = (uint32_t)(tt * TILE_K + sub * 16 + t);
            f32x4 acc[FR];
            __builtin_amdgcn_s_setprio(1);             // T5: cluster the MFMA burst
            #pragma unroll
            for (int f = 0; f < FR; ++f)
                acc[f] = __builtin_amdgcn_mfma_f32_16x16x32_f16(a[f][0], b0, ce, 0, 0, 0);
            #pragma unroll
            for (int f = 0; f < FR; ++f)
                acc[f] = __builtin_amdgcn_mfma_f32_16x16x32_f16(a[f][1], b1, acc[f], 0, 0, 0);
            __builtin_amdgcn_s_setprio(0);
            #pragma unroll
            for (int f = 0; f < FR; ++f) {
                // C/D layout: col = lane&15 (code), row = (lane>>4)*4 + i
                #pragma unroll
                for (int i = 0; i < 4; ++i) {
                    uint32_t k = (__float_as_uint(acc[f][i]) & 0xFFFFFC00u) | code; // v_and_or_b32
                    run[f][i] = umin32(run[f][i], k);                              // v_min_u32
                }
            }
        }
    }

    // ---- epilogue: cross-lane argmin, u16 index store, loss partials
    // R4-verified pattern: __shfl UNCONDITIONAL on all lanes; only the scalar
    // accumulate + store under the divergent (t==0) branch.  (R5 moved the shfl
    // inside the branch and lost 15/16 of the loss mass.)
    float lsum = 0.0f;
    #pragma unroll
    for (int f = 0; f < FR; ++f) {
        #pragma unroll
        for (int i = 0; i < 4; ++i) {
            uint32_t k = run[f][i];
            k = umin32(k, __shfl_xor(k, 1, 64));
            k = umin32(k, __shfl_xor(k, 2, 64));
            k = umin32(k, __shfl_xor(k, 4, 64));
            k = umin32(k, __shfl_xor(k, 8, 64));   // 16 lanes of each quarter now agree
            int   kw     = (int)(k & 1023u);
            float minval = __uint_as_float(k & 0xFFFFFC00u) - 0.5f;  // esq - 2*dot (truncated)
            int rloc = q * 4 + i;                  // row within this 16-row fragment
            int grow = r0 + f * 16 + rloc;         // global row
            float zs = __shfl(zsq[f], rloc, 64);   // ||z_g||^2 of row rloc (held by lane rloc)
            if (t == 0) {
                idx[(grow << 2) | g] = (unsigned short)kw;
                lsum += zs + minval;               // Σ_c (zq - zg)^2 for this (row, group)
            }
        }
    }
    #pragma unroll
    for (int off = 32; off; off >>= 1) lsum += __shfl_down(lsum, off, 64);

    if (lane == 0) ls[w] = lsum;
    __syncthreads();
    if (threadIdx.x == 0) {
        part[blockIdx.y * NBLKX + blockIdx.x] = ls[0] + ls[1] + ls[2] + ls[3];
    }
}

// ---------------- kernel 2: gather codebook rows -> streaming fp32 output
__global__ __launch_bounds__(256) void vq_gather(const unsigned short* __restrict__ idx,
                                                 const float* __restrict__ cb32,
                                                 float* __restrict__ out) {
    const int stride = gridDim.x * 256;
    const int total  = NTOK * (DDIM / 4);              // 16.7M float4s
    for (int i = blockIdx.x * 256 + threadIdx.x; i < total; i += stride) {
        int row = i >> 6;                              // output row
        int d4  = i & 63;                              // float4 index within row
        int g   = d4 >> 4;
        int c4  = d4 & 15;
        int k   = idx[(row << 2) | g];
        float4 v = *(const float4*)(cb32 + (size_t)(((g << 10) + k) << 6) + (c4 << 2));
        *(float4*)(out + ((size_t)row << 8) + (d4 << 2)) = v;
    }
}

// ---------------- finalize: reduce per-block partials into the loss scalar
__global__ __launch_bounds__(256) void vq_final(const float* __restrict__ part,
                                                float* __restrict__ out_loss) {
    __shared__ float ls[4];
    float s = 0.0f;
    for (int i = threadIdx.x; i < NPART; i += 256) s += part[i];
    #pragma unroll
    for (int off = 32; off; off >>= 1) s += __shfl_down(s, off, 64);
    int lane = threadIdx.x & 63, w = threadIdx.x >> 6;
    if (lane == 0) ls[w] = s;
    __syncthreads();
    if (threadIdx.x == 0) {
        // loss = mean_g(BETA*commit + embed) = 1.5 * total_sq_err / (N*D)
        *out_loss = 1.5f * (ls[0] + ls[1] + ls[2] + ls[3]) * (1.0f / ((float)NTOK * (float)DDIM));
    }
}

extern "C" void kernel_launch(void* const* d_in, const int* in_sizes, int n_in,
                              void* d_out, int out_size, void* d_ws, size_t ws_size,
                              hipStream_t stream) {
    const float* z  = (const float*)d_in[0];
    const float* cb = (const float*)d_in[1];
    float* out = (float*)d_out;

    char* ws = (char*)d_ws;
    f16*   cb16  = (f16*)ws;                                             // 512 KB
    float* esq05 = (float*)(ws + (size_t)GG * KCB * CC * sizeof(f16));   // 16 KB
    float* part  = (float*)(ws + 512*1024 + 16*1024);                    // 16 KB
    unsigned short* idx = (unsigned short*)(ws + 512*1024 + 32*1024);    // 2 MB (u16 x N x G)

    vq_prep<<<GG * KCB, 64, 0, stream>>>(cb, cb16, esq05);

    dim3 grid(NBLKX, GG);   // 1024 x 4
    vq_argmin<<<grid, 256, 0, stream>>>(z, cb16, esq05, idx, part);

    vq_gather<<<4096, 256, 0, stream>>>(idx, cb, out);

    vq_final<<<1, 256, 0, stream>>>(part, out + (size_t)NTOK * DDIM);
}